// Round 3
// baseline (429.252 us; speedup 1.0000x reference)
//
#include <hip/hip_runtime.h>

#define HH 224
#define WW 224
#define HWSZ (HH * WW)
#define NSTEPS 10
#define TH 32
#define CR 52            // TH + 2*NSTEPS rows of state per lane
#define NSTRIPS 7        // HH / TH
#define DT_C 0.15f
#define EXHALF (2 * 5 * CR)   // ints per exchange buffer (2 sides x 5 slots x CR rows)

typedef __fp16 h2 __attribute__((ext_vector_type(2)));

__device__ __forceinline__ int pack_sc(float s, float c) {
    h2 v = __builtin_amdgcn_cvt_pkrtz(s, c);
    union { h2 h; int i; } u; u.h = v;
    return u.i;
}
__device__ __forceinline__ void unpack_sc(int b, float& s, float& c) {
    union { int i; h2 h; } u; u.i = b;
    s = (float)u.h.x; c = (float)u.h.y;
}

__global__ __launch_bounds__(256)
void kuramoto_fused(const float* __restrict__ x_img,
                    const float* __restrict__ omega,
                    const float* __restrict__ Kp,
                    float* __restrict__ out)
{
    const int tx    = threadIdx.x;          // column x in [0,256), valid < 224
    const int wv    = tx >> 6;
    const int lane  = tx & 63;
    const int strip = blockIdx.x;
    const int img   = blockIdx.y;
    const int y0    = strip * TH - NSTEPS;  // first register row's global y

    // exchange[buf][side(0=R-cols,1=L-cols)][slot 0..4][row]; slot pads give free zeros
    __shared__ int exf[2 * EXHALF];
    for (int i = tx; i < 2 * EXHALF; i += 256) exf[i] = 0;

    const float DTK = DT_C * Kp[0];

    float s[CR], c[CR], dtom[CR];
    const bool xin = (tx < WW);
    const float* xrow = x_img + (size_t)img * HWSZ;

    #pragma unroll
    for (int y = 0; y < CR; ++y) {
        const int gy  = y0 + y;
        const bool in = xin && (gy >= 0) && (gy < HH);
        float xv = 0.f, om = 0.f;
        if (in) {
            xv = xrow[gy * WW + tx];
            om = omega[gy * WW + tx];
        }
        const float th = fmaf(6.28318530718f, xv, -3.14159265359f); // pi*(2x-1)
        s[y]    = in ? __sinf(th) : 0.f;   // out-of-image cells pinned to (0,0):
        c[y]    = in ? __cosf(th) : 0.f;   // (0,0) is a fixed point of the update
        dtom[y] = DT_C * om;
    }

    // boundary-column exchange addressing
    // read : lane0 -> [cur][0][wv][y]   (right col of wave wv-1; slot0 = zero pad)
    //        lane63-> [cur][1][wv+1][y] (left col of wave wv+1; slot4 = zero pad)
    // write: lane0 -> [nxt][1][wv][y],  lane63 -> [nxt][0][wv+1][y]
    const bool bnd  = (lane == 0) || (lane == 63);
    const int  rIdx = (lane == 63) ? ((1 * 5 + (wv + 1)) * CR) : ((0 * 5 + wv) * CR);
    const int  wIdx = (lane == 63) ? ((0 * 5 + (wv + 1)) * CR) : ((1 * 5 + wv) * CR);

    __syncthreads();                       // zero-fill visible
    if (bnd) {
        #pragma unroll
        for (int y = 1; y <= CR - 2; ++y)
            exf[wIdx + y] = pack_sc(s[y], c[y]);   // populate buffer 0
    }
    __syncthreads();

    #pragma unroll 1
    for (int t = 0; t < NSTEPS; ++t) {
        const int cur = (t & 1) ? EXHALF : 0;
        const int nxt = EXHALF - cur;
        float sm = s[0], cm = c[0];        // old y-1
        float s0 = s[1], c0 = c[1];        // old y
        #pragma unroll
        for (int y = 1; y <= CR - 2; ++y) {
            const float sp = s[y + 1], cp = c[y + 1];   // old y+1
            const int pk = pack_sc(s0, c0);
            int up = __shfl_up(pk, 1);                  // x-1 neighbor (fp16x2)
            int dn = __shfl_down(pk, 1);                // x+1 neighbor
            const int bv = exf[cur + rIdx + y];         // cross-wave boundary fix
            if (lane == 0)  up = bv;
            if (lane == 63) dn = bv;
            float sl, cl, sr, cr2;
            unpack_sc(up, sl, cl);
            unpack_sc(dn, sr, cr2);
            const float sn   = (sm + sp) + (sl + sr);
            const float cn   = (cm + cp) + (cl + cr2);
            const float coup = fmaf(c0, sn, -(s0 * cn));      // c*sin_n - s*cos_n
            const float d    = fmaf(DTK, coup, dtom[y]);      // |d| <= 0.3
            const float d2   = d * d;
            const float sd   = d * fmaf(d2, fmaf(d2, 8.33333333e-3f, -1.66666667e-1f), 1.f);
            const float cd   = fmaf(d2, fmaf(d2, 4.16666667e-2f, -5.0e-1f), 1.f);
            const float ns   = fmaf(c0, sd, s0 * cd);         // sin(th+d)
            const float nc   = fmaf(-s0, sd, c0 * cd);        // cos(th+d)
            s[y] = ns; c[y] = nc;
            if (bnd) exf[nxt + wIdx + y] = pack_sc(ns, nc);   // for next step
            sm = s0; cm = c0; s0 = sp; c0 = cp;               // slide window
        }
        __syncthreads();   // exchange buffer handoff between steps
    }

    if (xin) {
        float* ob = out + (size_t)img * (2 * HWSZ);
        #pragma unroll
        for (int y = NSTEPS; y < NSTEPS + TH; ++y) {
            const int gy = y0 + y;
            ob[gy * WW + tx]          = c[y];   // channel 0: cos
            ob[HWSZ + gy * WW + tx]   = s[y];   // channel 1: sin
        }
    }
}

extern "C" void kernel_launch(void* const* d_in, const int* in_sizes, int n_in,
                              void* d_out, int out_size, void* d_ws, size_t ws_size,
                              hipStream_t stream)
{
    const float* x_img = (const float*)d_in[0];
    const float* omega = (const float*)d_in[1];
    const float* K     = (const float*)d_in[2];
    float* out = (float*)d_out;
    const int B = in_sizes[0] / HWSZ;     // 256
    dim3 grid(NSTRIPS, B);
    kuramoto_fused<<<grid, dim3(256), 0, stream>>>(x_img, omega, K, out);
}

// Round 7
// 351.828 us; speedup vs baseline: 1.2201x; 1.2201x over previous
//
#include <hip/hip_runtime.h>

#define HH 224
#define WW 224
#define HWSZ (HH * WW)
#define NSTEPS 10
#define TH 32
#define CR 52            // TH + 2*NSTEPS rows of state per lane
#define NSTRIPS 7        // HH / TH
#define DT_C 0.15f
#define EXHALF (2 * 5 * CR)   // ints per exchange buffer (2 sides x 5 slots x CR rows)

typedef __fp16 h2 __attribute__((ext_vector_type(2)));

__device__ __forceinline__ int pack_sc(float s, float c) {
    h2 v = __builtin_amdgcn_cvt_pkrtz(s, c);
    union { h2 h; int i; } u; u.h = v;
    return u.i;
}
__device__ __forceinline__ float unpk0(int b) {   // sin half
    union { int i; h2 h; } u; u.i = b; return (float)u.h[0];
}
__device__ __forceinline__ float unpk1(int b) {   // cos half
    union { int i; h2 h; } u; u.i = b; return (float)u.h[1];
}

__global__ __launch_bounds__(256, 4)
void kuramoto_fused(const float* __restrict__ x_img,
                    const float* __restrict__ omega,
                    const float* __restrict__ Kp,
                    float* __restrict__ out)
{
    const int tx    = threadIdx.x;          // column x in [0,256), valid < 224
    const int wv    = tx >> 6;
    const int lane  = tx & 63;
    const int strip = blockIdx.x;
    const int img   = blockIdx.y;
    const int y0    = strip * TH - NSTEPS;  // first register row's global y

    // exchange[buf][side(0=R-cols,1=L-cols)][slot 0..4][row]; slot pads give free zeros
    __shared__ int exf[2 * EXHALF];
    for (int i = tx; i < 2 * EXHALF; i += 256) exf[i] = 0;

    const float DTK = DT_C * Kp[0];

    // Packed state: st[y] = fp16x2 (sin, cos).  dtom packed 2 rows per VGPR.
    int st[CR];
    int dt2[CR / 2];
    const bool xin = (tx < WW);
    const float* xrow = x_img + (size_t)img * HWSZ;

    #pragma unroll
    for (int y = 0; y < CR; y += 2) {
        float d01[2];
        #pragma unroll
        for (int k = 0; k < 2; ++k) {
            const int gy  = y0 + y + k;
            const bool in = xin && (gy >= 0) && (gy < HH);
            float xv = 0.f, om = 0.f;
            if (in) {
                xv = xrow[gy * WW + tx];
                om = omega[gy * WW + tx];
            }
            const float th = fmaf(6.28318530718f, xv, -3.14159265359f); // pi*(2x-1)
            const float sv = in ? __sinf(th) : 0.f;   // out-of-image pinned to (0,0):
            const float cv = in ? __cosf(th) : 0.f;   // (0,0) is a fixed point
            st[y + k] = pack_sc(sv, cv);
            d01[k] = DT_C * om;
        }
        dt2[y >> 1] = pack_sc(d01[0], d01[1]);
    }

    // boundary-column exchange addressing
    // read : lane0 -> [cur][0][wv][y]   (right col of wave wv-1; slot0 = zero pad)
    //        lane63-> [cur][1][wv+1][y] (left col of wave wv+1; slot4 = zero pad)
    // write: lane0 -> [nxt][1][wv][y],  lane63 -> [nxt][0][wv+1][y]
    const bool bnd  = (lane == 0) || (lane == 63);
    const int  rIdx = (lane == 63) ? ((1 * 5 + (wv + 1)) * CR) : ((0 * 5 + wv) * CR);
    const int  wIdx = (lane == 63) ? ((0 * 5 + (wv + 1)) * CR) : ((1 * 5 + wv) * CR);

    __syncthreads();                       // zero-fill visible
    if (bnd) {
        #pragma unroll
        for (int y = 1; y <= CR - 2; ++y)
            exf[wIdx + y] = st[y];         // already packed
    }
    __syncthreads();

    #pragma unroll 1
    for (int t = 0; t < NSTEPS; ++t) {
        const int cur = (t & 1) ? EXHALF : 0;
        const int nxt = EXHALF - cur;
        float sm = unpk0(st[0]), cm = unpk1(st[0]);   // old y-1
        float s0 = unpk0(st[1]), c0 = unpk1(st[1]);   // old y
        int   pk0 = st[1];                            // packed old y (for shuffle)
        #pragma unroll
        for (int y = 1; y <= CR - 2; ++y) {
            const int   pkp = st[y + 1];              // packed old y+1
            const float sp = unpk0(pkp), cp = unpk1(pkp);
            int up = __shfl_up(pk0, 1);               // x-1 neighbor (fp16x2)
            int dn = __shfl_down(pk0, 1);             // x+1 neighbor
            const int bv = exf[cur + rIdx + y];       // cross-wave boundary fix
            if (lane == 0)  up = bv;
            if (lane == 63) dn = bv;
            const float sl = unpk0(up), cl = unpk1(up);
            const float sr = unpk0(dn), cr2 = unpk1(dn);
            const float sn   = (sm + sp) + (sl + sr);
            const float cn   = (cm + cp) + (cl + cr2);
            const float coup = fmaf(c0, sn, -(s0 * cn));      // c*sin_n - s*cos_n
            const float dty  = (y & 1) ? unpk1(dt2[y >> 1]) : unpk0(dt2[y >> 1]);
            const float d    = fmaf(DTK, coup, dty);          // |d| <= 0.3
            const float d2   = d * d;
            const float sd   = d * fmaf(d2, fmaf(d2, 8.33333333e-3f, -1.66666667e-1f), 1.f);
            const float cd   = fmaf(d2, fmaf(d2, 4.16666667e-2f, -5.0e-1f), 1.f);
            const float ns   = fmaf(c0, sd, s0 * cd);         // sin(th+d)
            const float nc   = fmaf(-s0, sd, c0 * cd);        // cos(th+d)
            const int npk = pack_sc(ns, nc);
            st[y] = npk;
            if (bnd) exf[nxt + wIdx + y] = npk;               // for next step
            sm = s0; cm = c0; s0 = sp; c0 = cp; pk0 = pkp;    // slide window
        }
        __syncthreads();   // exchange buffer handoff between steps
    }

    if (xin) {
        float* ob = out + (size_t)img * (2 * HWSZ);
        #pragma unroll
        for (int y = NSTEPS; y < NSTEPS + TH; ++y) {
            const int gy = y0 + y;
            ob[gy * WW + tx]          = unpk1(st[y]);   // channel 0: cos
            ob[HWSZ + gy * WW + tx]   = unpk0(st[y]);   // channel 1: sin
        }
    }
}

extern "C" void kernel_launch(void* const* d_in, const int* in_sizes, int n_in,
                              void* d_out, int out_size, void* d_ws, size_t ws_size,
                              hipStream_t stream)
{
    const float* x_img = (const float*)d_in[0];
    const float* omega = (const float*)d_in[1];
    const float* K     = (const float*)d_in[2];
    float* out = (float*)d_out;
    const int B = in_sizes[0] / HWSZ;     // 256
    dim3 grid(NSTRIPS, B);
    kuramoto_fused<<<grid, dim3(256), 0, stream>>>(x_img, omega, K, out);
}